// Round 5
// baseline (110.466 us; speedup 1.0000x reference)
//
#include <hip/hip_runtime.h>
#include <hip/hip_bf16.h>

// Problem constants
#define BATCH 8
#define NN 2048
#define IN_F 256
#define OUT_F 128
#define ALPHA 0.2f

typedef __attribute__((ext_vector_type(8))) short short8v;
typedef __attribute__((ext_vector_type(4))) float f32x4;

// exact RTNE f32 -> bf16 bits
static __device__ __forceinline__ unsigned short f2bf(float x) {
    unsigned int u = __float_as_uint(x);
    u = (u + 0x7fffu + ((u >> 16) & 1u)) >> 16;
    return (unsigned short)u;
}

// ---------------------------------------------------------------------------
// Kernel 0: weight prep.
//   Wt[o][k] = bf16(Wcat[k][o]),  Wcat = [W1; W2]  (k in 0..511)
//   w1a1[k] = sum_o W1[k][o] * a[o],  w1a2[k] = sum_o W1[k][o] * a[128+o]
// ---------------------------------------------------------------------------
__global__ __launch_bounds__(256) void k_prew(
    const float* __restrict__ W1, const float* __restrict__ W2,
    const float* __restrict__ a,
    unsigned short* __restrict__ Wt, float* __restrict__ w1a1, float* __restrict__ w1a2)
{
    const int t = threadIdx.x;
    const int k8 = blockIdx.x * 8;
#pragma unroll
    for (int q = 0; q < 4; ++q) {
        const int idx = q * 256 + t;
        const int o = idx & 127;
        const int kk = k8 + (idx >> 7);
        const float v = (kk < IN_F) ? W1[kk * OUT_F + o] : W2[(kk - IN_F) * OUT_F + o];
        Wt[(size_t)o * 512 + kk] = f2bf(v);
    }
    if (k8 < IN_F) {
        const int lane = t & 63, w = t >> 6;
#pragma unroll
        for (int u = 0; u < 2; ++u) {
            const int kk = k8 + 2 * w + u;
            const float* wr = W1 + kk * OUT_F;
            float v1 = wr[lane] * a[lane] + wr[lane + 64] * a[lane + 64];
            float v2 = wr[lane] * a[OUT_F + lane] + wr[lane + 64] * a[OUT_F + lane + 64];
#pragma unroll
            for (int off = 32; off; off >>= 1) {
                v1 += __shfl_xor(v1, off);
                v2 += __shfl_xor(v2, off);
            }
            if (lane == 0) { w1a1[kk] = v1; w1a2[kk] = v2; }
        }
    }
}

// ---------------------------------------------------------------------------
// Kernel 1: projections via bf16 MFMA.
//   V = [h|j] @ Wcat -> Vt[b][o][n] bf16 ; s1 = h.w1a1 ; s2 = h.w1a2
// ---------------------------------------------------------------------------
#define BM 16

__global__ __launch_bounds__(256) void k_proj(
    const float* __restrict__ h, const float* __restrict__ j,
    const unsigned short* __restrict__ Wt,
    const float* __restrict__ w1a1g, const float* __restrict__ w1a2g,
    unsigned short* __restrict__ Vt, float* __restrict__ s1, float* __restrict__ s2)
{
    __shared__ __align__(16) unsigned short X[BM * 512];  // 16 KB, XOR-swizzled

    const int t = threadIdx.x, lane = t & 63, w = t >> 6;
    const int row0 = blockIdx.x * BM;
    const int b = row0 >> 11, n0 = row0 & 2047;

    const float4* wa1v = (const float4*)w1a1g;
    const float4* wa2v = (const float4*)w1a2g;

    // ---- stage h (k 0..255) + fused s-dots ----
#pragma unroll
    for (int q = 0; q < 4; ++q) {
        const int idx = q * 256 + t;
        const int row = idx >> 6, f4 = idx & 63;
        const float4 hv = ((const float4*)(h + (size_t)(row0 + row) * IN_F))[f4];
        union { unsigned long long ll; unsigned short u[4]; } pk;
        pk.u[0] = f2bf(hv.x); pk.u[1] = f2bf(hv.y); pk.u[2] = f2bf(hv.z); pk.u[3] = f2bf(hv.w);
        *(unsigned long long*)((char*)X + ((row * 1024 + f4 * 8) ^ ((row & 7) << 4))) = pk.ll;
        const float4 a1 = wa1v[f4], a2 = wa2v[f4];
        float d1 = hv.x * a1.x + hv.y * a1.y + hv.z * a1.z + hv.w * a1.w;
        float d2 = hv.x * a2.x + hv.y * a2.y + hv.z * a2.z + hv.w * a2.w;
#pragma unroll
        for (int off = 32; off; off >>= 1) {
            d1 += __shfl_xor(d1, off);
            d2 += __shfl_xor(d2, off);
        }
        if (lane == 0) { s1[row0 + row] = d1; s2[row0 + row] = d2; }
    }
    // ---- stage j (k 256..511) ----
#pragma unroll
    for (int q = 0; q < 4; ++q) {
        const int idx = q * 256 + t;
        const int row = idx >> 6, f4 = idx & 63;
        const float4 jv = ((const float4*)(j + (size_t)(row0 + row) * IN_F))[f4];
        union { unsigned long long ll; unsigned short u[4]; } pk;
        pk.u[0] = f2bf(jv.x); pk.u[1] = f2bf(jv.y); pk.u[2] = f2bf(jv.z); pk.u[3] = f2bf(jv.w);
        *(unsigned long long*)((char*)X + ((row * 1024 + 512 + f4 * 8) ^ ((row & 7) << 4))) = pk.ll;
    }
    __syncthreads();

    // ---- MFMA: D[m=row][n=o], A = X (LDS), B = Wt (L2-hot global) ----
    const unsigned short* wb = Wt + (size_t)(w * 32 + (lane & 15)) * 512 + ((lane >> 4) * 8);
    const int abase = (lane & 15) * 1024 + ((lane >> 4) * 16);
    const int aswz = (lane & 7) << 4;

    f32x4 acc0 = {0.f, 0.f, 0.f, 0.f}, acc1 = {0.f, 0.f, 0.f, 0.f};
#pragma unroll
    for (int ks = 0; ks < 16; ++ks) {
        const short8v af = *(const short8v*)((const char*)X + ((abase + ks * 64) ^ aswz));
        const short8v b0 = *(const short8v*)(wb + ks * 32);
        const short8v b1 = *(const short8v*)(wb + 16 * 512 + ks * 32);
        acc0 = __builtin_amdgcn_mfma_f32_16x16x32_bf16(af, b0, acc0, 0, 0, 0);
        acc1 = __builtin_amdgcn_mfma_f32_16x16x32_bf16(af, b1, acc1, 0, 0, 0);
    }

    const int nr = (lane >> 4) * 4;
#pragma unroll
    for (int f = 0; f < 2; ++f) {
        const f32x4 ac = f ? acc1 : acc0;
        const int o = w * 32 + f * 16 + (lane & 15);
        union { unsigned long long ll; unsigned short u[4]; } pk;
#pragma unroll
        for (int r = 0; r < 4; ++r) pk.u[r] = f2bf(ac[r]);
        *(unsigned long long*)(Vt + ((size_t)b * OUT_F + o) * NN + n0 + nr) = pk.ll;
    }
}

// ---------------------------------------------------------------------------
// Kernel 2: fused adj->bits + masked softmax + attention@V + ELU.
// IBLK=16 rows/block, grid 1024 (4 blocks/CU). 4 waves split k (512 each).
// Block reads its own 128 KB adj slice COALESCED (int4), packs to an LDS
// bitmask (16 x 264B padded), then runs the barrier-free register-P MFMA loop.
// B-frag P in registers; A-frag V from L2. End-of-kernel LDS combine.
// Fixed subtractor m_i = lrelu(s1_i + max_k s2_k) -> single pass, no rescale.
// LDS union: [s2 8KB | bits 4.2KB] during loop, comb 34.8KB after.
// ---------------------------------------------------------------------------
#define BSTRIDE 264   // bits row stride (bytes), padded: 264 = 8*33

__global__ __launch_bounds__(256, 4) void k_attn(
    const int* __restrict__ adj, const unsigned short* __restrict__ Vt,
    const float* __restrict__ s1g, const float* __restrict__ s2g,
    float* __restrict__ out)
{
    __shared__ __align__(16) char smem[4 * OUT_F * 17 * 4];  // 34816 B union
    __shared__ float rs_lds[4 * 16];
    __shared__ float wmaxs[4];

    float* s2_lds = (float*)smem;                       // [0 : 8192)
    unsigned char* bits_lds = (unsigned char*)smem + 8192;  // [8192 : 12416)
    float* comb = (float*)smem;                         // after loop: [0 : 34816)

    const int t = threadIdx.x, lane = t & 63, w = t >> 6;
    // XCD-bijective swizzle (grid 1024 % 8 == 0): each XCD owns one batch.
    const int orig = blockIdx.x;
    const int blk = (orig & 7) * 128 + (orig >> 3);
    const int b = blk >> 7;
    const int i0 = (blk & 127) << 4;

    const int irow = lane & 15;     // lane's output row (local); also V o-low bits
    const int kcb = lane >> 4;      // k-strip 0..3 within a 32-k step
    const int kw = w * 512;         // this wave's k-range

    // ---- adj -> LDS bits, coalesced. 16 rows x 512 int4 = 8192 units ----
    {
        const int4* ap4 = (const int4*)(adj + ((size_t)b * NN + i0) * NN);
#pragma unroll 4
        for (int i = 0; i < 32; ++i) {
            const int idx = i * 256 + t;
            const int4 x = ap4[idx];
            unsigned nib = 0;
            nib |= (x.x > 0) ? 1u : 0u;
            nib |= (x.y > 0) ? 2u : 0u;
            nib |= (x.z > 0) ? 4u : 0u;
            nib |= (x.w > 0) ? 8u : 0u;
            const unsigned pnib = (unsigned)__shfl_xor((int)nib, 1);
            if ((t & 1) == 0)
                bits_lds[(idx >> 9) * BSTRIDE + ((idx & 511) >> 1)] =
                    (unsigned char)(nib | (pnib << 4));
        }
    }

    // ---- stage s2 (full row) + global max ----
    const float4* s2v = (const float4*)(s2g + b * NN);
    float lmax = -1e30f;
#pragma unroll
    for (int q = 0; q < 2; ++q) {
        const int idx = q * 256 + t;
        const float4 v = s2v[idx];
        ((float4*)s2_lds)[idx] = v;
        lmax = fmaxf(fmaxf(lmax, fmaxf(v.x, v.y)), fmaxf(v.z, v.w));
    }
#pragma unroll
    for (int off = 32; off; off >>= 1) lmax = fmaxf(lmax, __shfl_xor(lmax, off));
    if (lane == 0) wmaxs[w] = lmax;

    const float s1r = s1g[b * NN + i0 + irow];
    __syncthreads();
    const float s2max = fmaxf(fmaxf(wmaxs[0], wmaxs[1]), fmaxf(wmaxs[2], wmaxs[3]));
    const float mx = s1r + s2max;
    const float mA = fmaxf(mx, ALPHA * mx);   // fixed subtractor, >= true row max

    // ---- preload this wave's bits from LDS (row irow, k-range kw..kw+511) ----
    unsigned long long breg[8];
    {
        const unsigned char* bp = bits_lds + irow * BSTRIDE + (kw >> 3);
#pragma unroll
        for (int q = 0; q < 8; ++q)
            breg[q] = *(const unsigned long long*)(bp + q * 8);
    }

    const float* s2p = s2_lds + kw + kcb * 8;
    const unsigned short* vb = Vt + ((size_t)b * OUT_F + irow) * NN + kw + kcb * 8;

    f32x4 acc[8];
#pragma unroll
    for (int og = 0; og < 8; ++og) acc[og] = (f32x4){0.f, 0.f, 0.f, 0.f};
    float psum = 0.f;

#pragma unroll
    for (int ks = 0; ks < 16; ++ks) {
        short8v vf[8];
#pragma unroll
        for (int og = 0; og < 8; ++og)
            vf[og] = *(const short8v*)(vb + ks * 32 + (size_t)og * 16 * NN);

        const float4 sa = *(const float4*)(s2p + ks * 32);
        const float4 sb = *(const float4*)(s2p + ks * 32 + 4);
        const float s2r[8] = {sa.x, sa.y, sa.z, sa.w, sb.x, sb.y, sb.z, sb.w};

        const unsigned sh = ((ks & 1) << 5) + (kcb << 3);
        const unsigned bb = (unsigned)((breg[ks >> 1] >> sh) & 0xff);

        union { short8v v; unsigned short u[8]; } pb;
#pragma unroll
        for (int e = 0; e < 8; ++e) {
            float x = s1r + s2r[e];
            x = fmaxf(x, ALPHA * x);           // leaky_relu
            float p = __expf(x - mA);
            p = (bb & (1u << e)) ? p : 0.f;
            psum += p;
            pb.u[e] = f2bf(p);
        }
#pragma unroll
        for (int og = 0; og < 8; ++og)
            acc[og] = __builtin_amdgcn_mfma_f32_16x16x32_bf16(vf[og], pb.v, acc[og], 0, 0, 0);
    }

    // ---- row sums: combine the 4 k-strips of this wave ----
    psum += __shfl_xor(psum, 16);
    psum += __shfl_xor(psum, 32);
    if (lane < 16) rs_lds[w * 16 + irow] = psum;

    __syncthreads();  // s2/bits dead; smem becomes comb
#pragma unroll
    for (int og = 0; og < 8; ++og)
#pragma unroll
        for (int r = 0; r < 4; ++r)
            comb[(w * OUT_F + og * 16 + kcb * 4 + r) * 17 + irow] = acc[og][r];
    __syncthreads();

    // ---- combine 4 wave-partials, normalize, ELU, coalesced f32 store ----
    const int i = t >> 4, oc = t & 15;
    const float tot = rs_lds[i] + rs_lds[16 + i] + rs_lds[32 + i] + rs_lds[48 + i];
    const float inv = 1.0f / tot;
    float res[8];
#pragma unroll
    for (int u = 0; u < 8; ++u) {
        const int o = oc * 8 + u;
        float v = comb[o * 17 + i] + comb[(OUT_F + o) * 17 + i]
                + comb[(2 * OUT_F + o) * 17 + i] + comb[(3 * OUT_F + o) * 17 + i];
        v *= inv;
        res[u] = (v > 0.f) ? v : expm1f(v);
    }
    float4* ob = (float4*)(out + ((size_t)b * NN + i0 + i) * OUT_F + oc * 8);
    ob[0] = make_float4(res[0], res[1], res[2], res[3]);
    ob[1] = make_float4(res[4], res[5], res[6], res[7]);
}

// ---------------------------------------------------------------------------
extern "C" void kernel_launch(void* const* d_in, const int* in_sizes, int n_in,
                              void* d_out, int out_size, void* d_ws, size_t ws_size,
                              hipStream_t stream) {
    const float* h  = (const float*)d_in[0];
    const float* j  = (const float*)d_in[1];
    const int* adj  = (const int*)d_in[2];
    const float* W1 = (const float*)d_in[3];
    const float* W2 = (const float*)d_in[4];
    const float* a  = (const float*)d_in[5];
    float* out = (float*)d_out;

    char* ws = (char*)d_ws;
    unsigned short* Vt = (unsigned short*)ws;               // 4 MB
    ws += (size_t)BATCH * OUT_F * NN * 2;
    float* s1 = (float*)ws; ws += (size_t)BATCH * NN * 4;   // 64 KB
    float* s2 = (float*)ws; ws += (size_t)BATCH * NN * 4;   // 64 KB
    unsigned short* Wt = (unsigned short*)ws; ws += 128 * 512 * 2;  // 128 KB
    float* w1a1 = (float*)ws; ws += 512 * 4;
    float* w1a2 = (float*)ws;

    k_prew<<<64, 256, 0, stream>>>(W1, W2, a, Wt, w1a1, w1a2);
    k_proj<<<(BATCH * NN) / BM, 256, 0, stream>>>(h, j, Wt, w1a1, w1a2, Vt, s1, s2);
    k_attn<<<(BATCH * NN) / 16, 256, 0, stream>>>(adj, Vt, s1, s2, out);
}

// Round 6
// 79.210 us; speedup vs baseline: 1.3946x; 1.3946x over previous
//
#include <hip/hip_runtime.h>
#include <hip/hip_bf16.h>

// Problem constants
#define BATCH 8
#define NN 2048
#define IN_F 256
#define OUT_F 128
#define ALPHA 0.2f

typedef __attribute__((ext_vector_type(8))) short short8v;
typedef __attribute__((ext_vector_type(4))) float f32x4;

// exact RTNE f32 -> bf16 bits
static __device__ __forceinline__ unsigned short f2bf(float x) {
    unsigned int u = __float_as_uint(x);
    u = (u + 0x7fffu + ((u >> 16) & 1u)) >> 16;
    return (unsigned short)u;
}

// ---------------------------------------------------------------------------
// Kernel 0: weight prep.
//   Wt[o][k] = bf16(Wcat[k][o]),  Wcat = [W1; W2]  (k in 0..511)
//   w1a1[k] = sum_o W1[k][o] * a[o],  w1a2[k] = sum_o W1[k][o] * a[128+o]
// ---------------------------------------------------------------------------
__global__ __launch_bounds__(256) void k_prew(
    const float* __restrict__ W1, const float* __restrict__ W2,
    const float* __restrict__ a,
    unsigned short* __restrict__ Wt, float* __restrict__ w1a1, float* __restrict__ w1a2)
{
    const int t = threadIdx.x;
    const int k8 = blockIdx.x * 8;
#pragma unroll
    for (int q = 0; q < 4; ++q) {
        const int idx = q * 256 + t;
        const int o = idx & 127;
        const int kk = k8 + (idx >> 7);
        const float v = (kk < IN_F) ? W1[kk * OUT_F + o] : W2[(kk - IN_F) * OUT_F + o];
        Wt[(size_t)o * 512 + kk] = f2bf(v);
    }
    if (k8 < IN_F) {
        const int lane = t & 63, w = t >> 6;
#pragma unroll
        for (int u = 0; u < 2; ++u) {
            const int kk = k8 + 2 * w + u;
            const float* wr = W1 + kk * OUT_F;
            float v1 = wr[lane] * a[lane] + wr[lane + 64] * a[lane + 64];
            float v2 = wr[lane] * a[OUT_F + lane] + wr[lane + 64] * a[OUT_F + lane + 64];
#pragma unroll
            for (int off = 32; off; off >>= 1) {
                v1 += __shfl_xor(v1, off);
                v2 += __shfl_xor(v2, off);
            }
            if (lane == 0) { w1a1[kk] = v1; w1a2[kk] = v2; }
        }
    }
}

// ---------------------------------------------------------------------------
// Kernel 1: projections via bf16 MFMA  +  coalesced adj->bitmask sweep.
//   V = [h|j] @ Wcat -> Vt[b][o][n] bf16 ; s1 = h.w1a1 ; s2 = h.w1a2
//   bits16[g]: bit e = (adj[g*16+e] > 0)   (dense 256 B per row)
// ---------------------------------------------------------------------------
#define BM 16

__global__ __launch_bounds__(256) void k_proj(
    const float* __restrict__ h, const float* __restrict__ j,
    const unsigned short* __restrict__ Wt,
    const float* __restrict__ w1a1g, const float* __restrict__ w1a2g,
    const int* __restrict__ adj,
    unsigned short* __restrict__ Vt, float* __restrict__ s1, float* __restrict__ s2,
    unsigned short* __restrict__ bits16)
{
    __shared__ __align__(16) unsigned short X[BM * 512];  // 16 KB, XOR-swizzled

    const int t = threadIdx.x, lane = t & 63, w = t >> 6;
    const int row0 = blockIdx.x * BM;
    const int b = row0 >> 11, n0 = row0 & 2047;

    const float4* wa1v = (const float4*)w1a1g;
    const float4* wa2v = (const float4*)w1a2g;

    // ---- stage h (k 0..255) + fused s-dots ----
#pragma unroll
    for (int q = 0; q < 4; ++q) {
        const int idx = q * 256 + t;
        const int row = idx >> 6, f4 = idx & 63;
        const float4 hv = ((const float4*)(h + (size_t)(row0 + row) * IN_F))[f4];
        union { unsigned long long ll; unsigned short u[4]; } pk;
        pk.u[0] = f2bf(hv.x); pk.u[1] = f2bf(hv.y); pk.u[2] = f2bf(hv.z); pk.u[3] = f2bf(hv.w);
        *(unsigned long long*)((char*)X + ((row * 1024 + f4 * 8) ^ ((row & 7) << 4))) = pk.ll;
        const float4 a1 = wa1v[f4], a2 = wa2v[f4];
        float d1 = hv.x * a1.x + hv.y * a1.y + hv.z * a1.z + hv.w * a1.w;
        float d2 = hv.x * a2.x + hv.y * a2.y + hv.z * a2.z + hv.w * a2.w;
#pragma unroll
        for (int off = 32; off; off >>= 1) {
            d1 += __shfl_xor(d1, off);
            d2 += __shfl_xor(d2, off);
        }
        if (lane == 0) { s1[row0 + row] = d1; s2[row0 + row] = d2; }
    }
    // ---- stage j (k 256..511) ----
#pragma unroll
    for (int q = 0; q < 4; ++q) {
        const int idx = q * 256 + t;
        const int row = idx >> 6, f4 = idx & 63;
        const float4 jv = ((const float4*)(j + (size_t)(row0 + row) * IN_F))[f4];
        union { unsigned long long ll; unsigned short u[4]; } pk;
        pk.u[0] = f2bf(jv.x); pk.u[1] = f2bf(jv.y); pk.u[2] = f2bf(jv.z); pk.u[3] = f2bf(jv.w);
        *(unsigned long long*)((char*)X + ((row * 1024 + 512 + f4 * 8) ^ ((row & 7) << 4))) = pk.ll;
    }
    __syncthreads();

    // ---- MFMA: D[m=row][n=o], A = X (LDS), B = Wt (L2-hot global) ----
    const unsigned short* wb = Wt + (size_t)(w * 32 + (lane & 15)) * 512 + ((lane >> 4) * 8);
    const int abase = (lane & 15) * 1024 + ((lane >> 4) * 16);
    const int aswz = (lane & 7) << 4;

    f32x4 acc0 = {0.f, 0.f, 0.f, 0.f}, acc1 = {0.f, 0.f, 0.f, 0.f};
#pragma unroll
    for (int ks = 0; ks < 16; ++ks) {
        const short8v af = *(const short8v*)((const char*)X + ((abase + ks * 64) ^ aswz));
        const short8v b0 = *(const short8v*)(wb + ks * 32);
        const short8v b1 = *(const short8v*)(wb + 16 * 512 + ks * 32);
        acc0 = __builtin_amdgcn_mfma_f32_16x16x32_bf16(af, b0, acc0, 0, 0, 0);
        acc1 = __builtin_amdgcn_mfma_f32_16x16x32_bf16(af, b1, acc1, 0, 0, 0);
    }

    const int nr = (lane >> 4) * 4;
#pragma unroll
    for (int f = 0; f < 2; ++f) {
        const f32x4 ac = f ? acc1 : acc0;
        const int o = w * 32 + f * 16 + (lane & 15);
        union { unsigned long long ll; unsigned short u[4]; } pk;
#pragma unroll
        for (int r = 0; r < 4; ++r) pk.u[r] = f2bf(ac[r]);
        *(unsigned long long*)(Vt + ((size_t)b * OUT_F + o) * NN + n0 + nr) = pk.ll;
    }

    // ---- coalesced adj -> bits sweep (grid-strided; 16 ints -> 16 bits/thread) ----
    const int gstride = 1024 * 256;
    for (int g = blockIdx.x * 256 + t; g < (BATCH * NN * NN) / 16; g += gstride) {
        const int4* ap = (const int4*)(adj + (size_t)g * 16);
        const int4 x0 = ap[0], x1 = ap[1], x2 = ap[2], x3 = ap[3];
        unsigned m = 0;
        m |= (x0.x > 0) ? 1u : 0u;        m |= (x0.y > 0) ? 2u : 0u;
        m |= (x0.z > 0) ? 4u : 0u;        m |= (x0.w > 0) ? 8u : 0u;
        m |= (x1.x > 0) ? 16u : 0u;       m |= (x1.y > 0) ? 32u : 0u;
        m |= (x1.z > 0) ? 64u : 0u;       m |= (x1.w > 0) ? 128u : 0u;
        m |= (x2.x > 0) ? 256u : 0u;      m |= (x2.y > 0) ? 512u : 0u;
        m |= (x2.z > 0) ? 1024u : 0u;     m |= (x2.w > 0) ? 2048u : 0u;
        m |= (x3.x > 0) ? 4096u : 0u;     m |= (x3.y > 0) ? 8192u : 0u;
        m |= (x3.z > 0) ? 16384u : 0u;    m |= (x3.w > 0) ? 32768u : 0u;
        bits16[g] = (unsigned short)m;
    }
}

// ---------------------------------------------------------------------------
// Kernel 2: masked softmax + attention@V + ELU. Barrier-free main loop.
// IBLK=32 rows (2 subtiles of 16), 4 waves split k (512 each), grid 512.
// V-fragment loads SOFTWARE-PIPELINED (vf[2][8] double buffer): step ks+1's
// 8 L2 loads issue before step ks's P-compute (~128 VALU ops) -> L2 latency
// covered in-wave. launch_bounds(256,2): VGPR cap 256 (grid is 2 blocks/CU
// anyway -> registers are free).
// bits pre-compressed in L2 (4 MB); 16 u64 preloaded per lane.
// Fixed subtractor m_i = lrelu(s1_i + max_k s2_k) -> single pass, no rescale.
// ---------------------------------------------------------------------------
#define IBLK 32

__global__ __launch_bounds__(256, 2) void k_attn(
    const unsigned char* __restrict__ bits, const unsigned short* __restrict__ Vt,
    const float* __restrict__ s1g, const float* __restrict__ s2g,
    float* __restrict__ out)
{
    __shared__ __align__(16) float s2_lds[NN];       // 8 KB
    __shared__ float comb[4 * OUT_F * 17];           // 34.8 KB
    __shared__ float rs_lds[4][IBLK];
    __shared__ float wmaxs[4];

    const int t = threadIdx.x, lane = t & 63, w = t >> 6;
    // XCD-bijective swizzle (grid 512 % 8 == 0): each XCD owns one batch.
    const int orig = blockIdx.x;
    const int blk = (orig & 7) * 64 + (orig >> 3);
    const int b = blk >> 6;
    const int i0 = (blk & 63) * IBLK;

    const int irow = lane & 15;     // subtile-local row; also V o-index low bits
    const int kcb = lane >> 4;      // k-strip 0..3 within a 32-k step
    const int kw = w * 512;         // this wave's k-range

    // ---- preload ALL adj bits for this wave's k-range (2 subtiles x 8 u64) ----
    unsigned long long breg0[8], breg1[8];
    {
        const unsigned char* bp0 = bits + ((size_t)b * NN + i0 + irow) * 256 + (kw >> 3);
        const unsigned char* bp1 = bp0 + 16 * 256;
#pragma unroll
        for (int q = 0; q < 8; ++q) {
            breg0[q] = *(const unsigned long long*)(bp0 + q * 8);
            breg1[q] = *(const unsigned long long*)(bp1 + q * 8);
        }
    }

    // ---- stage s2 (full row) + global max ----
    const float4* s2v = (const float4*)(s2g + b * NN);
    float lmax = -1e30f;
#pragma unroll
    for (int q = 0; q < 2; ++q) {
        const int idx = q * 256 + t;
        const float4 v = s2v[idx];
        ((float4*)s2_lds)[idx] = v;
        lmax = fmaxf(fmaxf(lmax, fmaxf(v.x, v.y)), fmaxf(v.z, v.w));
    }
#pragma unroll
    for (int off = 32; off; off >>= 1) lmax = fmaxf(lmax, __shfl_xor(lmax, off));
    if (lane == 0) wmaxs[w] = lmax;

    const float s1r0 = s1g[b * NN + i0 + irow];
    const float s1r1 = s1g[b * NN + i0 + 16 + irow];
    __syncthreads();
    const float s2max = fmaxf(fmaxf(wmaxs[0], wmaxs[1]), fmaxf(wmaxs[2], wmaxs[3]));
    const float mx0 = s1r0 + s2max, mx1 = s1r1 + s2max;
    const float mA0 = fmaxf(mx0, ALPHA * mx0);
    const float mA1 = fmaxf(mx1, ALPHA * mx1);

    const float* s2p = s2_lds + kw + kcb * 8;
    const unsigned short* vb = Vt + ((size_t)b * OUT_F + irow) * NN + kw + kcb * 8;

    f32x4 acc0[8], acc1[8];
#pragma unroll
    for (int og = 0; og < 8; ++og) {
        acc0[og] = (f32x4){0.f, 0.f, 0.f, 0.f};
        acc1[og] = (f32x4){0.f, 0.f, 0.f, 0.f};
    }
    float psum0 = 0.f, psum1 = 0.f;

    // ---- software-pipelined main loop ----
    short8v vf[2][8];             // double-buffered V fragments (static idx: full unroll)
#pragma unroll
    for (int og = 0; og < 8; ++og)
        vf[0][og] = *(const short8v*)(vb + (size_t)og * 16 * NN);
    float4 sa = *(const float4*)(s2p);
    float4 sb = *(const float4*)(s2p + 4);

#pragma unroll
    for (int ks = 0; ks < 16; ++ks) {
        const int cur = ks & 1, nxt = cur ^ 1;
        // issue next step's loads FIRST (latency covered by P-compute below)
        if (ks + 1 < 16) {
#pragma unroll
            for (int og = 0; og < 8; ++og)
                vf[nxt][og] = *(const short8v*)(vb + (ks + 1) * 32 + (size_t)og * 16 * NN);
        }
        float4 nsa, nsb;
        if (ks + 1 < 16) {
            nsa = *(const float4*)(s2p + (ks + 1) * 32);
            nsb = *(const float4*)(s2p + (ks + 1) * 32 + 4);
        }

        const float s2r[8] = {sa.x, sa.y, sa.z, sa.w, sb.x, sb.y, sb.z, sb.w};
        const unsigned sh = ((ks & 1) << 5) + (kcb << 3);
        const unsigned bb0 = (unsigned)((breg0[ks >> 1] >> sh) & 0xff);
        const unsigned bb1 = (unsigned)((breg1[ks >> 1] >> sh) & 0xff);

        union { short8v v; unsigned short u[8]; } pb0, pb1;
#pragma unroll
        for (int e = 0; e < 8; ++e) {
            float x0 = s1r0 + s2r[e];
            x0 = fmaxf(x0, ALPHA * x0);
            float p0 = __expf(x0 - mA0);
            p0 = (bb0 & (1u << e)) ? p0 : 0.f;
            psum0 += p0;
            pb0.u[e] = f2bf(p0);
            float x1 = s1r1 + s2r[e];
            x1 = fmaxf(x1, ALPHA * x1);
            float p1 = __expf(x1 - mA1);
            p1 = (bb1 & (1u << e)) ? p1 : 0.f;
            psum1 += p1;
            pb1.u[e] = f2bf(p1);
        }
#pragma unroll
        for (int og = 0; og < 8; ++og) {
            acc0[og] = __builtin_amdgcn_mfma_f32_16x16x32_bf16(vf[cur][og], pb0.v, acc0[og], 0, 0, 0);
            acc1[og] = __builtin_amdgcn_mfma_f32_16x16x32_bf16(vf[cur][og], pb1.v, acc1[og], 0, 0, 0);
        }
        if (ks + 1 < 16) { sa = nsa; sb = nsb; }
    }

    // ---- row sums: combine the 4 k-strips of this wave ----
    psum0 += __shfl_xor(psum0, 16); psum0 += __shfl_xor(psum0, 32);
    psum1 += __shfl_xor(psum1, 16); psum1 += __shfl_xor(psum1, 32);
    if (lane < 16) { rs_lds[w][irow] = psum0; rs_lds[w][16 + irow] = psum1; }

    // ---- combine round 0 (rows i0..i0+15) ----
#pragma unroll
    for (int og = 0; og < 8; ++og)
#pragma unroll
        for (int r = 0; r < 4; ++r)
            comb[(w * OUT_F + og * 16 + kcb * 4 + r) * 17 + irow] = acc0[og][r];
    __syncthreads();
    {
        const int i = t >> 4, oc = t & 15;
        const float tot = rs_lds[0][i] + rs_lds[1][i] + rs_lds[2][i] + rs_lds[3][i];
        const float inv = 1.0f / tot;
        float res[8];
#pragma unroll
        for (int u = 0; u < 8; ++u) {
            const int o = oc * 8 + u;
            float v = comb[o * 17 + i] + comb[(OUT_F + o) * 17 + i]
                    + comb[(2 * OUT_F + o) * 17 + i] + comb[(3 * OUT_F + o) * 17 + i];
            v *= inv;
            res[u] = (v > 0.f) ? v : expm1f(v);
        }
        float4* ob = (float4*)(out + ((size_t)b * NN + i0 + i) * OUT_F + oc * 8);
        ob[0] = make_float4(res[0], res[1], res[2], res[3]);
        ob[1] = make_float4(res[4], res[5], res[6], res[7]);
    }
    __syncthreads();

    // ---- combine round 1 (rows i0+16..i0+31) ----
#pragma unroll
    for (int og = 0; og < 8; ++og)
#pragma unroll
        for (int r = 0; r < 4; ++r)
            comb[(w * OUT_F + og * 16 + kcb * 4 + r) * 17 + irow] = acc1[og][r];
    __syncthreads();
    {
        const int i = t >> 4, oc = t & 15;
        const float tot = rs_lds[0][16 + i] + rs_lds[1][16 + i] + rs_lds[2][16 + i] + rs_lds[3][16 + i];
        const float inv = 1.0f / tot;
        float res[8];
#pragma unroll
        for (int u = 0; u < 8; ++u) {
            const int o = oc * 8 + u;
            float v = comb[o * 17 + i] + comb[(OUT_F + o) * 17 + i]
                    + comb[(2 * OUT_F + o) * 17 + i] + comb[(3 * OUT_F + o) * 17 + i];
            v *= inv;
            res[u] = (v > 0.f) ? v : expm1f(v);
        }
        float4* ob = (float4*)(out + ((size_t)b * NN + i0 + 16 + i) * OUT_F + oc * 8);
        ob[0] = make_float4(res[0], res[1], res[2], res[3]);
        ob[1] = make_float4(res[4], res[5], res[6], res[7]);
    }
}

// ---------------------------------------------------------------------------
extern "C" void kernel_launch(void* const* d_in, const int* in_sizes, int n_in,
                              void* d_out, int out_size, void* d_ws, size_t ws_size,
                              hipStream_t stream) {
    const float* h  = (const float*)d_in[0];
    const float* j  = (const float*)d_in[1];
    const int* adj  = (const int*)d_in[2];
    const float* W1 = (const float*)d_in[3];
    const float* W2 = (const float*)d_in[4];
    const float* a  = (const float*)d_in[5];
    float* out = (float*)d_out;

    char* ws = (char*)d_ws;
    unsigned short* Vt = (unsigned short*)ws;               // 4 MB
    ws += (size_t)BATCH * OUT_F * NN * 2;
    float* s1 = (float*)ws; ws += (size_t)BATCH * NN * 4;   // 64 KB
    float* s2 = (float*)ws; ws += (size_t)BATCH * NN * 4;   // 64 KB
    unsigned short* Wt = (unsigned short*)ws; ws += 128 * 512 * 2;  // 128 KB
    float* w1a1 = (float*)ws; ws += 512 * 4;
    float* w1a2 = (float*)ws; ws += 512 * 4;
    unsigned char* bits = (unsigned char*)ws;               // B*N*N/8 = 4 MB

    k_prew<<<64, 256, 0, stream>>>(W1, W2, a, Wt, w1a1, w1a2);
    k_proj<<<(BATCH * NN) / BM, 256, 0, stream>>>(h, j, Wt, w1a1, w1a2, adj,
                                                  Vt, s1, s2, (unsigned short*)bits);
    k_attn<<<(BATCH * NN) / IBLK, 256, 0, stream>>>(bits, Vt, s1, s2, out);
}

// Round 7
// 78.270 us; speedup vs baseline: 1.4114x; 1.0120x over previous
//
#include <hip/hip_runtime.h>
#include <hip/hip_bf16.h>

// Problem constants
#define BATCH 8
#define NN 2048
#define IN_F 256
#define OUT_F 128
#define ALPHA 0.2f

typedef __attribute__((ext_vector_type(8))) short short8v;
typedef __attribute__((ext_vector_type(4))) float f32x4;

// exact RTNE f32 -> bf16 bits
static __device__ __forceinline__ unsigned short f2bf(float x) {
    unsigned int u = __float_as_uint(x);
    u = (u + 0x7fffu + ((u >> 16) & 1u)) >> 16;
    return (unsigned short)u;
}

// ---------------------------------------------------------------------------
// Kernel 0: weight prep.
//   Wt[o][k] = bf16(Wcat[k][o]),  Wcat = [W1; W2]  (k in 0..511)
//   w1a1[k] = sum_o W1[k][o] * a[o],  w1a2[k] = sum_o W1[k][o] * a[128+o]
// ---------------------------------------------------------------------------
__global__ __launch_bounds__(256) void k_prew(
    const float* __restrict__ W1, const float* __restrict__ W2,
    const float* __restrict__ a,
    unsigned short* __restrict__ Wt, float* __restrict__ w1a1, float* __restrict__ w1a2)
{
    const int t = threadIdx.x;
    const int k8 = blockIdx.x * 8;
#pragma unroll
    for (int q = 0; q < 4; ++q) {
        const int idx = q * 256 + t;
        const int o = idx & 127;
        const int kk = k8 + (idx >> 7);
        const float v = (kk < IN_F) ? W1[kk * OUT_F + o] : W2[(kk - IN_F) * OUT_F + o];
        Wt[(size_t)o * 512 + kk] = f2bf(v);
    }
    if (k8 < IN_F) {
        const int lane = t & 63, w = t >> 6;
#pragma unroll
        for (int u = 0; u < 2; ++u) {
            const int kk = k8 + 2 * w + u;
            const float* wr = W1 + kk * OUT_F;
            float v1 = wr[lane] * a[lane] + wr[lane + 64] * a[lane + 64];
            float v2 = wr[lane] * a[OUT_F + lane] + wr[lane + 64] * a[OUT_F + lane + 64];
#pragma unroll
            for (int off = 32; off; off >>= 1) {
                v1 += __shfl_xor(v1, off);
                v2 += __shfl_xor(v2, off);
            }
            if (lane == 0) { w1a1[kk] = v1; w1a2[kk] = v2; }
        }
    }
}

// ---------------------------------------------------------------------------
// Kernel 1: projections via bf16 MFMA  +  coalesced adj->bitmask sweep.
//   V = [h|j] @ Wcat -> Vt[b][o][n] bf16 ; s1 = h.w1a1 ; s2 = h.w1a2
//   bits16[g]: bit e = (adj[g*16+e] > 0)
// ---------------------------------------------------------------------------
#define BM 16

__global__ __launch_bounds__(256) void k_proj(
    const float* __restrict__ h, const float* __restrict__ j,
    const unsigned short* __restrict__ Wt,
    const float* __restrict__ w1a1g, const float* __restrict__ w1a2g,
    const int* __restrict__ adj,
    unsigned short* __restrict__ Vt, float* __restrict__ s1, float* __restrict__ s2,
    unsigned short* __restrict__ bits16)
{
    __shared__ __align__(16) unsigned short X[BM * 512];  // 16 KB, XOR-swizzled

    const int t = threadIdx.x, lane = t & 63, w = t >> 6;
    const int row0 = blockIdx.x * BM;
    const int b = row0 >> 11, n0 = row0 & 2047;

    const float4* wa1v = (const float4*)w1a1g;
    const float4* wa2v = (const float4*)w1a2g;

    // ---- stage h (k 0..255) + fused s-dots ----
#pragma unroll
    for (int q = 0; q < 4; ++q) {
        const int idx = q * 256 + t;
        const int row = idx >> 6, f4 = idx & 63;
        const float4 hv = ((const float4*)(h + (size_t)(row0 + row) * IN_F))[f4];
        union { unsigned long long ll; unsigned short u[4]; } pk;
        pk.u[0] = f2bf(hv.x); pk.u[1] = f2bf(hv.y); pk.u[2] = f2bf(hv.z); pk.u[3] = f2bf(hv.w);
        *(unsigned long long*)((char*)X + ((row * 1024 + f4 * 8) ^ ((row & 7) << 4))) = pk.ll;
        const float4 a1 = wa1v[f4], a2 = wa2v[f4];
        float d1 = hv.x * a1.x + hv.y * a1.y + hv.z * a1.z + hv.w * a1.w;
        float d2 = hv.x * a2.x + hv.y * a2.y + hv.z * a2.z + hv.w * a2.w;
#pragma unroll
        for (int off = 32; off; off >>= 1) {
            d1 += __shfl_xor(d1, off);
            d2 += __shfl_xor(d2, off);
        }
        if (lane == 0) { s1[row0 + row] = d1; s2[row0 + row] = d2; }
    }
    // ---- stage j (k 256..511) ----
#pragma unroll
    for (int q = 0; q < 4; ++q) {
        const int idx = q * 256 + t;
        const int row = idx >> 6, f4 = idx & 63;
        const float4 jv = ((const float4*)(j + (size_t)(row0 + row) * IN_F))[f4];
        union { unsigned long long ll; unsigned short u[4]; } pk;
        pk.u[0] = f2bf(jv.x); pk.u[1] = f2bf(jv.y); pk.u[2] = f2bf(jv.z); pk.u[3] = f2bf(jv.w);
        *(unsigned long long*)((char*)X + ((row * 1024 + 512 + f4 * 8) ^ ((row & 7) << 4))) = pk.ll;
    }
    __syncthreads();

    // ---- MFMA: D[m=row][n=o], A = X (LDS), B = Wt (L2-hot global) ----
    const unsigned short* wb = Wt + (size_t)(w * 32 + (lane & 15)) * 512 + ((lane >> 4) * 8);
    const int abase = (lane & 15) * 1024 + ((lane >> 4) * 16);
    const int aswz = (lane & 7) << 4;

    f32x4 acc0 = {0.f, 0.f, 0.f, 0.f}, acc1 = {0.f, 0.f, 0.f, 0.f};
#pragma unroll
    for (int ks = 0; ks < 16; ++ks) {
        const short8v af = *(const short8v*)((const char*)X + ((abase + ks * 64) ^ aswz));
        const short8v b0 = *(const short8v*)(wb + ks * 32);
        const short8v b1 = *(const short8v*)(wb + 16 * 512 + ks * 32);
        acc0 = __builtin_amdgcn_mfma_f32_16x16x32_bf16(af, b0, acc0, 0, 0, 0);
        acc1 = __builtin_amdgcn_mfma_f32_16x16x32_bf16(af, b1, acc1, 0, 0, 0);
    }

    const int nr = (lane >> 4) * 4;
#pragma unroll
    for (int f = 0; f < 2; ++f) {
        const f32x4 ac = f ? acc1 : acc0;
        const int o = w * 32 + f * 16 + (lane & 15);
        union { unsigned long long ll; unsigned short u[4]; } pk;
#pragma unroll
        for (int r = 0; r < 4; ++r) pk.u[r] = f2bf(ac[r]);
        *(unsigned long long*)(Vt + ((size_t)b * OUT_F + o) * NN + n0 + nr) = pk.ll;
    }

    // ---- coalesced adj -> bits sweep (grid-strided; 16 ints -> 16 bits/thread) ----
    const int gstride = 1024 * 256;
    for (int g = blockIdx.x * 256 + t; g < (BATCH * NN * NN) / 16; g += gstride) {
        const int4* ap = (const int4*)(adj + (size_t)g * 16);
        const int4 x0 = ap[0], x1 = ap[1], x2 = ap[2], x3 = ap[3];
        unsigned m = 0;
        m |= (x0.x > 0) ? 1u : 0u;        m |= (x0.y > 0) ? 2u : 0u;
        m |= (x0.z > 0) ? 4u : 0u;        m |= (x0.w > 0) ? 8u : 0u;
        m |= (x1.x > 0) ? 16u : 0u;       m |= (x1.y > 0) ? 32u : 0u;
        m |= (x1.z > 0) ? 64u : 0u;       m |= (x1.w > 0) ? 128u : 0u;
        m |= (x2.x > 0) ? 256u : 0u;      m |= (x2.y > 0) ? 512u : 0u;
        m |= (x2.z > 0) ? 1024u : 0u;     m |= (x2.w > 0) ? 2048u : 0u;
        m |= (x3.x > 0) ? 4096u : 0u;     m |= (x3.y > 0) ? 8192u : 0u;
        m |= (x3.z > 0) ? 16384u : 0u;    m |= (x3.w > 0) ? 32768u : 0u;
        bits16[g] = (unsigned short)m;
    }
}

// ---------------------------------------------------------------------------
// Kernel 2: masked softmax + attention@V + ELU.
// o-SPLIT: 2 blocks per 32-row tile, each computes 64 of 128 out-cols, full k.
// Grid 1024, 4 waves/block, launch_bounds(256,4) -> 4 blocks/CU = 4 waves/SIMD.
// Waves split k 4-way (512 each, 16 steps of 32). Barrier-free main loop.
// VALU trims: nibble->float4 mask LUT (1 mul/elem), psum via MFMA ones-row,
// v_cvt_pk_bf16_f32 packing. Bits in bank-padded LDS [32][65] words.
// Fixed subtractor m_i = lrelu(s1_i + max_k s2_k) -> single pass, no rescale.
// ---------------------------------------------------------------------------
#define IBLK 32

__global__ __launch_bounds__(256, 4) void k_attn(
    const unsigned char* __restrict__ bits, const unsigned short* __restrict__ Vt,
    const float* __restrict__ s1g, const float* __restrict__ s2g,
    float* __restrict__ out)
{
    __shared__ __align__(16) char smem[33792];   // union: [s2 8192 | bits 8320] -> comb
    __shared__ float rs_lds[4][IBLK];
    __shared__ float wmaxs[4];
    __shared__ __align__(16) float lut[16][4];

    float* s2_lds = (float*)smem;
    unsigned int* bitw = (unsigned int*)(smem + 8192);   // [32][65] words, padded
    float* comb = (float*)smem;                           // [4][64][33] floats

    const int t = threadIdx.x, lane = t & 63, w = t >> 6;
    // XCD swizzle: batch = XCD. grid 1024 = 8 batches x (64 row-tiles x 2 o-halves)
    const int orig = blockIdx.x;
    const int b = orig & 7;
    const int r = orig >> 3;
    const int oh = r >> 6;              // o-half: cols oh*64 .. +63
    const int i0 = (r & 63) * IBLK;

    // mask LUT: nibble -> 4 floats
    if (t < 16) {
        lut[t][0] = (float)(t & 1);
        lut[t][1] = (float)((t >> 1) & 1);
        lut[t][2] = (float)((t >> 2) & 1);
        lut[t][3] = (float)((t >> 3) & 1);
    }

    // ---- stage bits: 32 rows x 64 words -> padded stride 65 (bank-clean) ----
    {
        const unsigned int* bg = (const unsigned int*)(bits + ((size_t)b * NN + i0) * 256);
#pragma unroll
        for (int q = 0; q < 8; ++q) {
            const int idx = q * 256 + t;   // 0..2047
            bitw[(idx >> 6) * 65 + (idx & 63)] = bg[idx];
        }
    }

    // ---- stage s2 (full row) + global max ----
    const float4* s2v = (const float4*)(s2g + b * NN);
    float lmax = -1e30f;
#pragma unroll
    for (int q = 0; q < 2; ++q) {
        const int idx = q * 256 + t;
        const float4 v = s2v[idx];
        ((float4*)s2_lds)[idx] = v;
        lmax = fmaxf(fmaxf(lmax, fmaxf(v.x, v.y)), fmaxf(v.z, v.w));
    }
#pragma unroll
    for (int off = 32; off; off >>= 1) lmax = fmaxf(lmax, __shfl_xor(lmax, off));
    if (lane == 0) wmaxs[w] = lmax;

    const int irow = lane & 15;     // subtile-local row; also V o-index low bits
    const int kcb = lane >> 4;      // k-strip 0..3 within a 32-k step
    const int kw = w * 512;         // this wave's k-range

    const float s1r0 = s1g[b * NN + i0 + irow];
    const float s1r1 = s1g[b * NN + i0 + 16 + irow];
    __syncthreads();
    const float s2max = fmaxf(fmaxf(wmaxs[0], wmaxs[1]), fmaxf(wmaxs[2], wmaxs[3]));
    const float mx0 = s1r0 + s2max, mx1 = s1r1 + s2max;
    const float mA0 = fmaxf(mx0, ALPHA * mx0);
    const float mA1 = fmaxf(mx1, ALPHA * mx1);

    const float* s2p = s2_lds + kw + kcb * 8;
    const unsigned short* vb =
        Vt + ((size_t)b * OUT_F + oh * 64 + irow) * NN + kw + kcb * 8;
    const unsigned int* bw0p = bitw + irow * 65 + w * 16;
    const unsigned int* bw1p = bitw + (16 + irow) * 65 + w * 16;

    short8v vone;
#pragma unroll
    for (int q = 0; q < 8; ++q) vone[q] = (short)0x3F80;  // bf16 1.0

    f32x4 acc0[4], acc1[4];
    f32x4 acc_ps0 = {0.f, 0.f, 0.f, 0.f}, acc_ps1 = {0.f, 0.f, 0.f, 0.f};
#pragma unroll
    for (int og = 0; og < 4; ++og) {
        acc0[og] = (f32x4){0.f, 0.f, 0.f, 0.f};
        acc1[og] = (f32x4){0.f, 0.f, 0.f, 0.f};
    }

#pragma unroll
    for (int ks = 0; ks < 16; ++ks) {
        // V fragments (loads first: P-compute below covers L2 latency)
        const short8v vf0 = *(const short8v*)(vb + ks * 32);
        const short8v vf1 = *(const short8v*)(vb + ks * 32 + 16 * NN);
        const short8v vf2 = *(const short8v*)(vb + ks * 32 + 32 * NN);
        const short8v vf3 = *(const short8v*)(vb + ks * 32 + 48 * NN);

        const unsigned int bb0 = (bw0p[ks] >> (kcb * 8)) & 0xffu;
        const unsigned int bb1 = (bw1p[ks] >> (kcb * 8)) & 0xffu;
        const float4 m00 = ((const float4*)lut)[bb0 & 15], m01 = ((const float4*)lut)[bb0 >> 4];
        const float4 m10 = ((const float4*)lut)[bb1 & 15], m11 = ((const float4*)lut)[bb1 >> 4];

        const float4 sa = *(const float4*)(s2p + ks * 32);
        const float4 sb = *(const float4*)(s2p + ks * 32 + 4);
        const float s2r[8] = {sa.x, sa.y, sa.z, sa.w, sb.x, sb.y, sb.z, sb.w};
        const float mk0[8] = {m00.x, m00.y, m00.z, m00.w, m01.x, m01.y, m01.z, m01.w};
        const float mk1[8] = {m10.x, m10.y, m10.z, m10.w, m11.x, m11.y, m11.z, m11.w};

        float p0[8], p1[8];
#pragma unroll
        for (int e = 0; e < 8; ++e) {
            float x0 = s1r0 + s2r[e];
            x0 = fmaxf(x0, ALPHA * x0);
            p0[e] = __expf(x0 - mA0) * mk0[e];
            float x1 = s1r1 + s2r[e];
            x1 = fmaxf(x1, ALPHA * x1);
            p1[e] = __expf(x1 - mA1) * mk1[e];
        }
        union { short8v v; unsigned int u32[4]; } pb0, pb1;
#pragma unroll
        for (int q = 0; q < 4; ++q) {
            asm("v_cvt_pk_bf16_f32 %0, %1, %2" : "=v"(pb0.u32[q]) : "v"(p0[2 * q]), "v"(p0[2 * q + 1]));
            asm("v_cvt_pk_bf16_f32 %0, %1, %2" : "=v"(pb1.u32[q]) : "v"(p1[2 * q]), "v"(p1[2 * q + 1]));
        }

        // psum via ones-row MFMA (sums all 32 k of the step in f32)
        acc_ps0 = __builtin_amdgcn_mfma_f32_16x16x32_bf16(vone, pb0.v, acc_ps0, 0, 0, 0);
        acc_ps1 = __builtin_amdgcn_mfma_f32_16x16x32_bf16(vone, pb1.v, acc_ps1, 0, 0, 0);
        acc0[0] = __builtin_amdgcn_mfma_f32_16x16x32_bf16(vf0, pb0.v, acc0[0], 0, 0, 0);
        acc1[0] = __builtin_amdgcn_mfma_f32_16x16x32_bf16(vf0, pb1.v, acc1[0], 0, 0, 0);
        acc0[1] = __builtin_amdgcn_mfma_f32_16x16x32_bf16(vf1, pb0.v, acc0[1], 0, 0, 0);
        acc1[1] = __builtin_amdgcn_mfma_f32_16x16x32_bf16(vf1, pb1.v, acc1[1], 0, 0, 0);
        acc0[2] = __builtin_amdgcn_mfma_f32_16x16x32_bf16(vf2, pb0.v, acc0[2], 0, 0, 0);
        acc1[2] = __builtin_amdgcn_mfma_f32_16x16x32_bf16(vf2, pb1.v, acc1[2], 0, 0, 0);
        acc0[3] = __builtin_amdgcn_mfma_f32_16x16x32_bf16(vf3, pb0.v, acc0[3], 0, 0, 0);
        acc1[3] = __builtin_amdgcn_mfma_f32_16x16x32_bf16(vf3, pb1.v, acc1[3], 0, 0, 0);
    }

    // ---- wave-partial row sums: every lane already holds its row's total ----
    if (lane < 16) {
        rs_lds[w][lane] = acc_ps0[0];
        rs_lds[w][16 + lane] = acc_ps1[0];
    }

    __syncthreads();  // s2/bits dead; smem becomes comb
#pragma unroll
    for (int og = 0; og < 4; ++og) {
#pragma unroll
        for (int rr = 0; rr < 4; ++rr) {
            const int ol = og * 16 + kcb * 4 + rr;
            comb[(w * 64 + ol) * 33 + irow] = acc0[og][rr];
            comb[(w * 64 + ol) * 33 + 16 + irow] = acc1[og][rr];
        }
    }
    __syncthreads();

    // ---- combine 4 wave-partials, normalize, ELU, coalesced f32 store ----
    const int i = t >> 3, oc = t & 7;
    const float tot = rs_lds[0][i] + rs_lds[1][i] + rs_lds[2][i] + rs_lds[3][i];
    const float inv = 1.0f / tot;
    float res[8];
#pragma unroll
    for (int u = 0; u < 8; ++u) {
        const int ol = oc * 8 + u;
        float v = comb[ol * 33 + i] + comb[(64 + ol) * 33 + i]
                + comb[(128 + ol) * 33 + i] + comb[(192 + ol) * 33 + i];
        v *= inv;
        res[u] = (v > 0.f) ? v : expm1f(v);
    }
    float4* ob = (float4*)(out + ((size_t)b * NN + i0 + i) * OUT_F + oh * 64 + oc * 8);
    ob[0] = make_float4(res[0], res[1], res[2], res[3]);
    ob[1] = make_float4(res[4], res[5], res[6], res[7]);
}

// ---------------------------------------------------------------------------
extern "C" void kernel_launch(void* const* d_in, const int* in_sizes, int n_in,
                              void* d_out, int out_size, void* d_ws, size_t ws_size,
                              hipStream_t stream) {
    const float* h  = (const float*)d_in[0];
    const float* j  = (const float*)d_in[1];
    const int* adj  = (const int*)d_in[2];
    const float* W1 = (const float*)d_in[3];
    const float* W2 = (const float*)d_in[4];
    const float* a  = (const float*)d_in[5];
    float* out = (float*)d_out;

    char* ws = (char*)d_ws;
    unsigned short* Vt = (unsigned short*)ws;               // 4 MB
    ws += (size_t)BATCH * OUT_F * NN * 2;
    float* s1 = (float*)ws; ws += (size_t)BATCH * NN * 4;   // 64 KB
    float* s2 = (float*)ws; ws += (size_t)BATCH * NN * 4;   // 64 KB
    unsigned short* Wt = (unsigned short*)ws; ws += 128 * 512 * 2;  // 128 KB
    float* w1a1 = (float*)ws; ws += 512 * 4;
    float* w1a2 = (float*)ws; ws += 512 * 4;
    unsigned char* bits = (unsigned char*)ws;               // B*N*N/8 = 4 MB

    k_prew<<<64, 256, 0, stream>>>(W1, W2, a, Wt, w1a1, w1a2);
    k_proj<<<(BATCH * NN) / BM, 256, 0, stream>>>(h, j, Wt, w1a1, w1a2, adj,
                                                  Vt, s1, s2, (unsigned short*)bits);
    k_attn<<<(BATCH * NN) / IBLK * 2, 256, 0, stream>>>(bits, Vt, s1, s2, out);
}

// Round 8
// 72.493 us; speedup vs baseline: 1.5238x; 1.0797x over previous
//
#include <hip/hip_runtime.h>
#include <hip/hip_bf16.h>

// Problem constants
#define BATCH 8
#define NN 2048
#define IN_F 256
#define OUT_F 128
#define ALPHA 0.2f

typedef __attribute__((ext_vector_type(8))) short short8v;
typedef __attribute__((ext_vector_type(4))) float f32x4;

// exact RTNE f32 -> bf16 bits
static __device__ __forceinline__ unsigned short f2bf(float x) {
    unsigned int u = __float_as_uint(x);
    u = (u + 0x7fffu + ((u >> 16) & 1u)) >> 16;
    return (unsigned short)u;
}

// ---------------------------------------------------------------------------
// Kernel 0: weight prep.
//   Wt[o][k] = bf16(Wcat[k][o]),  Wcat = [W1; W2]  (k in 0..511)
//   w1a1[k] = sum_o W1[k][o] * a[o],  w1a2[k] = sum_o W1[k][o] * a[128+o]
// ---------------------------------------------------------------------------
__global__ __launch_bounds__(256) void k_prew(
    const float* __restrict__ W1, const float* __restrict__ W2,
    const float* __restrict__ a,
    unsigned short* __restrict__ Wt, float* __restrict__ w1a1, float* __restrict__ w1a2)
{
    const int t = threadIdx.x;
    const int k8 = blockIdx.x * 8;
#pragma unroll
    for (int q = 0; q < 4; ++q) {
        const int idx = q * 256 + t;
        const int o = idx & 127;
        const int kk = k8 + (idx >> 7);
        const float v = (kk < IN_F) ? W1[kk * OUT_F + o] : W2[(kk - IN_F) * OUT_F + o];
        Wt[(size_t)o * 512 + kk] = f2bf(v);
    }
    if (k8 < IN_F) {
        const int lane = t & 63, w = t >> 6;
#pragma unroll
        for (int u = 0; u < 2; ++u) {
            const int kk = k8 + 2 * w + u;
            const float* wr = W1 + kk * OUT_F;
            float v1 = wr[lane] * a[lane] + wr[lane + 64] * a[lane + 64];
            float v2 = wr[lane] * a[OUT_F + lane] + wr[lane + 64] * a[OUT_F + lane + 64];
#pragma unroll
            for (int off = 32; off; off >>= 1) {
                v1 += __shfl_xor(v1, off);
                v2 += __shfl_xor(v2, off);
            }
            if (lane == 0) { w1a1[kk] = v1; w1a2[kk] = v2; }
        }
    }
}

// ---------------------------------------------------------------------------
// Kernel 1: projections via bf16 MFMA  +  coalesced adj->bitmask sweep.
//   V = [h|j] @ Wcat, stored FRAGMENT-MAJOR:
//     Vf byte addr = b*512K + (n>>5)*8192 + o*64 + ((n&31)>>3)*16 + (n&7)*2
//   (a wave's MFMA A-fragment load is then a dense, fully-consumed 1 KB)
//   s1 = h.w1a1 ; s2 = h.w1a2 ; bits16[g]: bit e = (adj[g*16+e] > 0)
// ---------------------------------------------------------------------------
#define BM 16

__global__ __launch_bounds__(256) void k_proj(
    const float* __restrict__ h, const float* __restrict__ j,
    const unsigned short* __restrict__ Wt,
    const float* __restrict__ w1a1g, const float* __restrict__ w1a2g,
    const int* __restrict__ adj,
    unsigned short* __restrict__ Vf, float* __restrict__ s1, float* __restrict__ s2,
    unsigned short* __restrict__ bits16)
{
    __shared__ __align__(16) unsigned short X[BM * 512];  // 16 KB, XOR-swizzled

    const int t = threadIdx.x, lane = t & 63, w = t >> 6;
    const int row0 = blockIdx.x * BM;
    const int b = row0 >> 11, n0 = row0 & 2047;

    const float4* wa1v = (const float4*)w1a1g;
    const float4* wa2v = (const float4*)w1a2g;

    // ---- stage h (k 0..255) + fused s-dots ----
#pragma unroll
    for (int q = 0; q < 4; ++q) {
        const int idx = q * 256 + t;
        const int row = idx >> 6, f4 = idx & 63;
        const float4 hv = ((const float4*)(h + (size_t)(row0 + row) * IN_F))[f4];
        union { unsigned long long ll; unsigned short u[4]; } pk;
        pk.u[0] = f2bf(hv.x); pk.u[1] = f2bf(hv.y); pk.u[2] = f2bf(hv.z); pk.u[3] = f2bf(hv.w);
        *(unsigned long long*)((char*)X + ((row * 1024 + f4 * 8) ^ ((row & 7) << 4))) = pk.ll;
        const float4 a1 = wa1v[f4], a2 = wa2v[f4];
        float d1 = hv.x * a1.x + hv.y * a1.y + hv.z * a1.z + hv.w * a1.w;
        float d2 = hv.x * a2.x + hv.y * a2.y + hv.z * a2.z + hv.w * a2.w;
#pragma unroll
        for (int off = 32; off; off >>= 1) {
            d1 += __shfl_xor(d1, off);
            d2 += __shfl_xor(d2, off);
        }
        if (lane == 0) { s1[row0 + row] = d1; s2[row0 + row] = d2; }
    }
    // ---- stage j (k 256..511) ----
#pragma unroll
    for (int q = 0; q < 4; ++q) {
        const int idx = q * 256 + t;
        const int row = idx >> 6, f4 = idx & 63;
        const float4 jv = ((const float4*)(j + (size_t)(row0 + row) * IN_F))[f4];
        union { unsigned long long ll; unsigned short u[4]; } pk;
        pk.u[0] = f2bf(jv.x); pk.u[1] = f2bf(jv.y); pk.u[2] = f2bf(jv.z); pk.u[3] = f2bf(jv.w);
        *(unsigned long long*)((char*)X + ((row * 1024 + 512 + f4 * 8) ^ ((row & 7) << 4))) = pk.ll;
    }
    __syncthreads();

    // ---- MFMA: D[m=row][n=o], A = X (LDS), B = Wt (L2-hot global) ----
    const unsigned short* wb = Wt + (size_t)(w * 32 + (lane & 15)) * 512 + ((lane >> 4) * 8);
    const int abase = (lane & 15) * 1024 + ((lane >> 4) * 16);
    const int aswz = (lane & 7) << 4;

    f32x4 acc0 = {0.f, 0.f, 0.f, 0.f}, acc1 = {0.f, 0.f, 0.f, 0.f};
#pragma unroll
    for (int ks = 0; ks < 16; ++ks) {
        const short8v af = *(const short8v*)((const char*)X + ((abase + ks * 64) ^ aswz));
        const short8v b0 = *(const short8v*)(wb + ks * 32);
        const short8v b1 = *(const short8v*)(wb + 16 * 512 + ks * 32);
        acc0 = __builtin_amdgcn_mfma_f32_16x16x32_bf16(af, b0, acc0, 0, 0, 0);
        acc1 = __builtin_amdgcn_mfma_f32_16x16x32_bf16(af, b1, acc1, 0, 0, 0);
    }

    // ---- store Vf fragment-major: lane holds n = n0+(lane>>4)*4 .. +3, col o ----
    const int nn = n0 + (lane >> 4) * 4;
    const size_t vbase = (size_t)b * 524288
                       + ((size_t)(nn >> 5) << 13)
                       + (((nn & 31) >> 3) << 4) + ((nn & 7) << 1);
#pragma unroll
    for (int f = 0; f < 2; ++f) {
        const f32x4 ac = f ? acc1 : acc0;
        const int o = w * 32 + f * 16 + (lane & 15);
        union { unsigned long long ll; unsigned short u[4]; } pk;
#pragma unroll
        for (int r = 0; r < 4; ++r) pk.u[r] = f2bf(ac[r]);
        *(unsigned long long*)((char*)Vf + vbase + o * 64) = pk.ll;
    }

    // ---- coalesced adj -> bits sweep (grid-strided; 16 ints -> 16 bits/thread) ----
    const int gstride = 1024 * 256;
    for (int g = blockIdx.x * 256 + t; g < (BATCH * NN * NN) / 16; g += gstride) {
        const int4* ap = (const int4*)(adj + (size_t)g * 16);
        const int4 x0 = ap[0], x1 = ap[1], x2 = ap[2], x3 = ap[3];
        unsigned m = 0;
        m |= (x0.x > 0) ? 1u : 0u;        m |= (x0.y > 0) ? 2u : 0u;
        m |= (x0.z > 0) ? 4u : 0u;        m |= (x0.w > 0) ? 8u : 0u;
        m |= (x1.x > 0) ? 16u : 0u;       m |= (x1.y > 0) ? 32u : 0u;
        m |= (x1.z > 0) ? 64u : 0u;       m |= (x1.w > 0) ? 128u : 0u;
        m |= (x2.x > 0) ? 256u : 0u;      m |= (x2.y > 0) ? 512u : 0u;
        m |= (x2.z > 0) ? 1024u : 0u;     m |= (x2.w > 0) ? 2048u : 0u;
        m |= (x3.x > 0) ? 4096u : 0u;     m |= (x3.y > 0) ? 8192u : 0u;
        m |= (x3.z > 0) ? 16384u : 0u;    m |= (x3.w > 0) ? 32768u : 0u;
        bits16[g] = (unsigned short)m;
    }
}

// ---------------------------------------------------------------------------
// Kernel 2: masked softmax + attention@V + ELU.
// Same structure as round 7 (o-split 64, k-split 4, grid 1024) EXCEPT:
//  - V loads are DENSE 1 KB fragment-major loads (no 16-row gather)
//  - f2bf scalar pack (m240: hand-written cvt_pk asm regresses)
//  - launch_bounds(256,3): VGPR cap ~168 (spill-safe), 12 waves/CU
// Fixed subtractor m_i = lrelu(s1_i + max_k s2_k) -> single pass, no rescale.
// ---------------------------------------------------------------------------
#define IBLK 32

__global__ __launch_bounds__(256, 3) void k_attn(
    const unsigned char* __restrict__ bits, const unsigned short* __restrict__ Vf,
    const float* __restrict__ s1g, const float* __restrict__ s2g,
    float* __restrict__ out)
{
    __shared__ __align__(16) char smem[33792];   // union: [s2 8192 | bits 8320] -> comb
    __shared__ float rs_lds[4][IBLK];
    __shared__ float wmaxs[4];
    __shared__ __align__(16) float lut[16][4];

    float* s2_lds = (float*)smem;
    unsigned int* bitw = (unsigned int*)(smem + 8192);   // [32][65] words, padded
    float* comb = (float*)smem;                           // [4][64][33] floats

    const int t = threadIdx.x, lane = t & 63, w = t >> 6;
    // XCD swizzle: batch = XCD. grid 1024 = 8 batches x (64 row-tiles x 2 o-halves)
    const int orig = blockIdx.x;
    const int b = orig & 7;
    const int r = orig >> 3;
    const int oh = r >> 6;              // o-half: cols oh*64 .. +63
    const int i0 = (r & 63) * IBLK;

    // mask LUT: nibble -> 4 floats
    if (t < 16) {
        lut[t][0] = (float)(t & 1);
        lut[t][1] = (float)((t >> 1) & 1);
        lut[t][2] = (float)((t >> 2) & 1);
        lut[t][3] = (float)((t >> 3) & 1);
    }

    // ---- stage bits: 32 rows x 64 words -> padded stride 65 (bank-clean) ----
    {
        const unsigned int* bg = (const unsigned int*)(bits + ((size_t)b * NN + i0) * 256);
#pragma unroll
        for (int q = 0; q < 8; ++q) {
            const int idx = q * 256 + t;   // 0..2047
            bitw[(idx >> 6) * 65 + (idx & 63)] = bg[idx];
        }
    }

    // ---- stage s2 (full row) + global max ----
    const float4* s2v = (const float4*)(s2g + b * NN);
    float lmax = -1e30f;
#pragma unroll
    for (int q = 0; q < 2; ++q) {
        const int idx = q * 256 + t;
        const float4 v = s2v[idx];
        ((float4*)s2_lds)[idx] = v;
        lmax = fmaxf(fmaxf(lmax, fmaxf(v.x, v.y)), fmaxf(v.z, v.w));
    }
#pragma unroll
    for (int off = 32; off; off >>= 1) lmax = fmaxf(lmax, __shfl_xor(lmax, off));
    if (lane == 0) wmaxs[w] = lmax;

    const int irow = lane & 15;     // subtile-local row
    const int kcb = lane >> 4;      // k-strip 0..3 within a 32-k step
    const int kw = w * 512;         // this wave's k-range

    const float s1r0 = s1g[b * NN + i0 + irow];
    const float s1r1 = s1g[b * NN + i0 + 16 + irow];
    __syncthreads();
    const float s2max = fmaxf(fmaxf(wmaxs[0], wmaxs[1]), fmaxf(wmaxs[2], wmaxs[3]));
    const float mx0 = s1r0 + s2max, mx1 = s1r1 + s2max;
    const float mA0 = fmaxf(mx0, ALPHA * mx0);
    const float mA1 = fmaxf(mx1, ALPHA * mx1);

    const float* s2p = s2_lds + kw + kcb * 8;
    // Fragment-major V base: this wave's k-blocks start at (kw/32)=w*16;
    // lane offset irow*64 + kcb*16 makes each og-load a dense 1 KB.
    const char* vfb = (const char*)Vf + (size_t)b * 524288 + (size_t)(w * 16) * 8192
                    + (size_t)(oh * 64 + irow) * 64 + (size_t)kcb * 16;
    const unsigned int* bw0p = bitw + irow * 65 + w * 16;
    const unsigned int* bw1p = bitw + (16 + irow) * 65 + w * 16;

    short8v vone;
#pragma unroll
    for (int q = 0; q < 8; ++q) vone[q] = (short)0x3F80;  // bf16 1.0

    f32x4 acc0[4], acc1[4];
    f32x4 acc_ps0 = {0.f, 0.f, 0.f, 0.f}, acc_ps1 = {0.f, 0.f, 0.f, 0.f};
#pragma unroll
    for (int og = 0; og < 4; ++og) {
        acc0[og] = (f32x4){0.f, 0.f, 0.f, 0.f};
        acc1[og] = (f32x4){0.f, 0.f, 0.f, 0.f};
    }

#pragma unroll
    for (int ks = 0; ks < 16; ++ks) {
        // V fragments: dense 1 KB loads (loads first: P-compute covers latency)
        const char* vk = vfb + (size_t)ks * 8192;
        const short8v vf0 = *(const short8v*)(vk);
        const short8v vf1 = *(const short8v*)(vk + 1024);
        const short8v vf2 = *(const short8v*)(vk + 2048);
        const short8v vf3 = *(const short8v*)(vk + 3072);

        const unsigned int bb0 = (bw0p[ks] >> (kcb * 8)) & 0xffu;
        const unsigned int bb1 = (bw1p[ks] >> (kcb * 8)) & 0xffu;
        const float4 m00 = ((const float4*)lut)[bb0 & 15], m01 = ((const float4*)lut)[bb0 >> 4];
        const float4 m10 = ((const float4*)lut)[bb1 & 15], m11 = ((const float4*)lut)[bb1 >> 4];

        const float4 sa = *(const float4*)(s2p + ks * 32);
        const float4 sb = *(const float4*)(s2p + ks * 32 + 4);
        const float s2r[8] = {sa.x, sa.y, sa.z, sa.w, sb.x, sb.y, sb.z, sb.w};
        const float mk0[8] = {m00.x, m00.y, m00.z, m00.w, m01.x, m01.y, m01.z, m01.w};
        const float mk1[8] = {m10.x, m10.y, m10.z, m10.w, m11.x, m11.y, m11.z, m11.w};

        union { short8v v; unsigned short u[8]; } pb0, pb1;
#pragma unroll
        for (int e = 0; e < 8; ++e) {
            float x0 = s1r0 + s2r[e];
            x0 = fmaxf(x0, ALPHA * x0);
            pb0.u[e] = f2bf(__expf(x0 - mA0) * mk0[e]);
            float x1 = s1r1 + s2r[e];
            x1 = fmaxf(x1, ALPHA * x1);
            pb1.u[e] = f2bf(__expf(x1 - mA1) * mk1[e]);
        }

        // psum via ones-row MFMA (sums all 32 k of the step in f32)
        acc_ps0 = __builtin_amdgcn_mfma_f32_16x16x32_bf16(vone, pb0.v, acc_ps0, 0, 0, 0);
        acc_ps1 = __builtin_amdgcn_mfma_f32_16x16x32_bf16(vone, pb1.v, acc_ps1, 0, 0, 0);
        acc0[0] = __builtin_amdgcn_mfma_f32_16x16x32_bf16(vf0, pb0.v, acc0[0], 0, 0, 0);
        acc1[0] = __builtin_amdgcn_mfma_f32_16x16x32_bf16(vf0, pb1.v, acc1[0], 0, 0, 0);
        acc0[1] = __builtin_amdgcn_mfma_f32_16x16x32_bf16(vf1, pb0.v, acc0[1], 0, 0, 0);
        acc1[1] = __builtin_amdgcn_mfma_f32_16x16x32_bf16(vf1, pb1.v, acc1[1], 0, 0, 0);
        acc0[2] = __builtin_amdgcn_mfma_f32_16x16x32_bf16(vf2, pb0.v, acc0[2], 0, 0, 0);
        acc1[2] = __builtin_amdgcn_mfma_f32_16x16x32_bf16(vf2, pb1.v, acc1[2], 0, 0, 0);
        acc0[3] = __builtin_amdgcn_mfma_f32_16x16x32_bf16(vf3, pb0.v, acc0[3], 0, 0, 0);
        acc1[3] = __builtin_amdgcn_mfma_f32_16x16x32_bf16(vf3, pb1.v, acc1[3], 0, 0, 0);
    }

    // ---- wave-partial row sums: every lane already holds its row's total ----
    if (lane < 16) {
        rs_lds[w][lane] = acc_ps0[0];
        rs_lds[w][16 + lane] = acc_ps1[0];
    }

    __syncthreads();  // s2/bits dead; smem becomes comb
#pragma unroll
    for (int og = 0; og < 4; ++og) {
#pragma unroll
        for (int rr = 0; rr < 4; ++rr) {
            const int ol = og * 16 + kcb * 4 + rr;
            comb[(w * 64 + ol) * 33 + irow] = acc0[og][rr];
            comb[(w * 64 + ol) * 33 + 16 + irow] = acc1[og][rr];
        }
    }
    __syncthreads();

    // ---- combine 4 wave-partials, normalize, ELU, coalesced f32 store ----
    const int i = t >> 3, oc = t & 7;
    const float tot = rs_lds[0][i] + rs_lds[1][i] + rs_lds[2][i] + rs_lds[3][i];
    const float inv = 1.0f / tot;
    float res[8];
#pragma unroll
    for (int u = 0; u < 8; ++u) {
        const int ol = oc * 8 + u;
        float v = comb[ol * 33 + i] + comb[(64 + ol) * 33 + i]
                + comb[(128 + ol) * 33 + i] + comb[(192 + ol) * 33 + i];
        v *= inv;
        res[u] = (v > 0.f) ? v : expm1f(v);
    }
    float4* ob = (float4*)(out + ((size_t)b * NN + i0 + i) * OUT_F + oh * 64 + oc * 8);
    ob[0] = make_float4(res[0], res[1], res[2], res[3]);
    ob[1] = make_float4(res[4], res[5], res[6], res[7]);
}

// ---------------------------------------------------------------------------
extern "C" void kernel_launch(void* const* d_in, const int* in_sizes, int n_in,
                              void* d_out, int out_size, void* d_ws, size_t ws_size,
                              hipStream_t stream) {
    const float* h  = (const float*)d_in[0];
    const float* j  = (const float*)d_in[1];
    const int* adj  = (const int*)d_in[2];
    const float* W1 = (const float*)d_in[3];
    const float* W2 = (const float*)d_in[4];
    const float* a  = (const float*)d_in[5];
    float* out = (float*)d_out;

    char* ws = (char*)d_ws;
    unsigned short* Vf = (unsigned short*)ws;               // 4 MB fragment-major
    ws += (size_t)BATCH * OUT_F * NN * 2;
    float* s1 = (float*)ws; ws += (size_t)BATCH * NN * 4;   // 64 KB
    float* s2 = (float*)ws; ws += (size_t)BATCH * NN * 4;   // 64 KB
    unsigned short* Wt = (unsigned short*)ws; ws += 128 * 512 * 2;  // 128 KB
    float* w1a1 = (float*)ws; ws += 512 * 4;
    float* w1a2 = (float*)ws; ws += 512 * 4;
    unsigned char* bits = (unsigned char*)ws;               // B*N*N/8 = 4 MB

    k_prew<<<64, 256, 0, stream>>>(W1, W2, a, Wt, w1a1, w1a2);
    k_proj<<<(BATCH * NN) / BM, 256, 0, stream>>>(h, j, Wt, w1a1, w1a2, adj,
                                                  Vf, s1, s2, (unsigned short*)bits);
    k_attn<<<(BATCH * NN) / IBLK * 2, 256, 0, stream>>>(bits, Vf, s1, s2, out);
}

// Round 9
// 68.737 us; speedup vs baseline: 1.6071x; 1.0546x over previous
//
#include <hip/hip_runtime.h>
#include <hip/hip_bf16.h>

// Problem constants
#define BATCH 8
#define NN 2048
#define IN_F 256
#define OUT_F 128
#define ALPHA 0.2f

typedef __attribute__((ext_vector_type(8))) short short8v;
typedef __attribute__((ext_vector_type(4))) float f32x4;

// exact RTNE f32 -> bf16 bits (scalar fallback; hot paths use cvt_pk intrinsics)
static __device__ __forceinline__ unsigned short f2bf(float x) {
    unsigned int u = __float_as_uint(x);
    u = (u + 0x7fffu + ((u >> 16) & 1u)) >> 16;
    return (unsigned short)u;
}

// pack 4 floats -> 4 bf16 (8 B) via v_cvt_pk_bf16_f32 (RTNE, compiler-emitted)
static __device__ __forceinline__ unsigned long long pk4(float a, float b, float c, float d) {
    union { unsigned long long ll; __hip_bfloat162 h2[2]; } u;
    u.h2[0] = __float22bfloat162_rn(make_float2(a, b));
    u.h2[1] = __float22bfloat162_rn(make_float2(c, d));
    return u.ll;
}

// ---------------------------------------------------------------------------
// Kernel 0: weight prep.
//   Wt[o][k] = bf16(Wcat[k][o]),  Wcat = [W1; W2]  (k in 0..511)
//   w1a1[k] = sum_o W1[k][o] * a[o],  w1a2[k] = sum_o W1[k][o] * a[128+o]
// ---------------------------------------------------------------------------
__global__ __launch_bounds__(256) void k_prew(
    const float* __restrict__ W1, const float* __restrict__ W2,
    const float* __restrict__ a,
    unsigned short* __restrict__ Wt, float* __restrict__ w1a1, float* __restrict__ w1a2)
{
    const int t = threadIdx.x;
    const int k8 = blockIdx.x * 8;
#pragma unroll
    for (int q = 0; q < 4; ++q) {
        const int idx = q * 256 + t;
        const int o = idx & 127;
        const int kk = k8 + (idx >> 7);
        const float v = (kk < IN_F) ? W1[kk * OUT_F + o] : W2[(kk - IN_F) * OUT_F + o];
        Wt[(size_t)o * 512 + kk] = f2bf(v);
    }
    if (k8 < IN_F) {
        const int lane = t & 63, w = t >> 6;
#pragma unroll
        for (int u = 0; u < 2; ++u) {
            const int kk = k8 + 2 * w + u;
            const float* wr = W1 + kk * OUT_F;
            float v1 = wr[lane] * a[lane] + wr[lane + 64] * a[lane + 64];
            float v2 = wr[lane] * a[OUT_F + lane] + wr[lane + 64] * a[OUT_F + lane + 64];
#pragma unroll
            for (int off = 32; off; off >>= 1) {
                v1 += __shfl_xor(v1, off);
                v2 += __shfl_xor(v2, off);
            }
            if (lane == 0) { w1a1[kk] = v1; w1a2[kk] = v2; }
        }
    }
}

// ---------------------------------------------------------------------------
// Kernel 1: projections via bf16 MFMA  +  coalesced adj->bitmask sweep.
//   V = [h|j] @ Wcat, stored FRAGMENT-MAJOR:
//     Vf byte addr = b*512K + (n>>5)*8192 + o*64 + ((n&31)>>3)*16 + (n&7)*2
//   s1 = h.w1a1 ; s2 = h.w1a2  (f32, per-lane accumulated; ONE shfl reduce)
//   bits16[g]: bit e = (adj[g*16+e] > 0)
// Staging mapping: lane owns row srow=w*4+(lane>>4) for all 4 iterations ->
// s-dot partials accumulate in registers, no serial shfl chains in the loop.
// ---------------------------------------------------------------------------
#define BM 16

__global__ __launch_bounds__(256) void k_proj(
    const float* __restrict__ h, const float* __restrict__ j,
    const unsigned short* __restrict__ Wt,
    const float* __restrict__ w1a1g, const float* __restrict__ w1a2g,
    const int* __restrict__ adj,
    unsigned short* __restrict__ Vf, float* __restrict__ s1, float* __restrict__ s2,
    unsigned short* __restrict__ bits16)
{
    __shared__ __align__(16) unsigned short X[BM * 512];  // 16 KB, XOR-swizzled

    const int t = threadIdx.x, lane = t & 63, w = t >> 6;
    const int row0 = blockIdx.x * BM;
    const int b = row0 >> 11, n0 = row0 & 2047;

    const float4* wa1v = (const float4*)w1a1g;
    const float4* wa2v = (const float4*)w1a2g;

    const int srow = w * 4 + (lane >> 4);   // this lane's staging row (fixed)
    const int scol = lane & 15;
    const int sswz = (srow & 7) << 4;
    const float* hrow = h + (size_t)(row0 + srow) * IN_F;
    const float* jrow = j + (size_t)(row0 + srow) * IN_F;

    float d1 = 0.f, d2 = 0.f;
    // ---- stage h (k 0..255), accumulate s-dot partials per lane ----
#pragma unroll
    for (int q = 0; q < 4; ++q) {
        const int f4 = q * 16 + scol;
        const float4 hv = ((const float4*)hrow)[f4];
        *(unsigned long long*)((char*)X + ((srow * 1024 + f4 * 8) ^ sswz)) =
            pk4(hv.x, hv.y, hv.z, hv.w);
        const float4 a1 = wa1v[f4], a2 = wa2v[f4];
        d1 += hv.x * a1.x + hv.y * a1.y + hv.z * a1.z + hv.w * a1.w;
        d2 += hv.x * a2.x + hv.y * a2.y + hv.z * a2.z + hv.w * a2.w;
    }
    // ---- stage j (k 256..511) ----
#pragma unroll
    for (int q = 0; q < 4; ++q) {
        const int f4 = q * 16 + scol;
        const float4 jv = ((const float4*)jrow)[f4];
        *(unsigned long long*)((char*)X + ((srow * 1024 + 512 + f4 * 8) ^ sswz)) =
            pk4(jv.x, jv.y, jv.z, jv.w);
    }
    // ---- single 4-step reduction over the 16 lanes of the row group ----
    d1 += __shfl_xor(d1, 1); d1 += __shfl_xor(d1, 2);
    d1 += __shfl_xor(d1, 4); d1 += __shfl_xor(d1, 8);
    d2 += __shfl_xor(d2, 1); d2 += __shfl_xor(d2, 2);
    d2 += __shfl_xor(d2, 4); d2 += __shfl_xor(d2, 8);
    if (scol == 0) { s1[row0 + srow] = d1; s2[row0 + srow] = d2; }
    __syncthreads();

    // ---- MFMA: D[m=row][n=o], A = X (LDS), B = Wt (L2-hot global) ----
    const unsigned short* wb = Wt + (size_t)(w * 32 + (lane & 15)) * 512 + ((lane >> 4) * 8);
    const int abase = (lane & 15) * 1024 + ((lane >> 4) * 16);
    const int aswz = (lane & 7) << 4;

    f32x4 acc0 = {0.f, 0.f, 0.f, 0.f}, acc1 = {0.f, 0.f, 0.f, 0.f};
#pragma unroll
    for (int ks = 0; ks < 16; ++ks) {
        const short8v af = *(const short8v*)((const char*)X + ((abase + ks * 64) ^ aswz));
        const short8v b0 = *(const short8v*)(wb + ks * 32);
        const short8v b1 = *(const short8v*)(wb + 16 * 512 + ks * 32);
        acc0 = __builtin_amdgcn_mfma_f32_16x16x32_bf16(af, b0, acc0, 0, 0, 0);
        acc1 = __builtin_amdgcn_mfma_f32_16x16x32_bf16(af, b1, acc1, 0, 0, 0);
    }

    // ---- store Vf fragment-major: lane holds n = n0+(lane>>4)*4 .. +3, col o ----
    const int nn = n0 + (lane >> 4) * 4;
    const size_t vbase = (size_t)b * 524288
                       + ((size_t)(nn >> 5) << 13)
                       + (((nn & 31) >> 3) << 4) + ((nn & 7) << 1);
#pragma unroll
    for (int f = 0; f < 2; ++f) {
        const f32x4 ac = f ? acc1 : acc0;
        const int o = w * 32 + f * 16 + (lane & 15);
        *(unsigned long long*)((char*)Vf + vbase + o * 64) = pk4(ac[0], ac[1], ac[2], ac[3]);
    }

    // ---- coalesced adj -> bits sweep (grid-strided; 16 ints -> 16 bits/thread) ----
    const int gstride = 1024 * 256;
    for (int g = blockIdx.x * 256 + t; g < (BATCH * NN * NN) / 16; g += gstride) {
        const int4* ap = (const int4*)(adj + (size_t)g * 16);
        const int4 x0 = ap[0], x1 = ap[1], x2 = ap[2], x3 = ap[3];
        unsigned m = 0;
        m |= (x0.x > 0) ? 1u : 0u;        m |= (x0.y > 0) ? 2u : 0u;
        m |= (x0.z > 0) ? 4u : 0u;        m |= (x0.w > 0) ? 8u : 0u;
        m |= (x1.x > 0) ? 16u : 0u;       m |= (x1.y > 0) ? 32u : 0u;
        m |= (x1.z > 0) ? 64u : 0u;       m |= (x1.w > 0) ? 128u : 0u;
        m |= (x2.x > 0) ? 256u : 0u;      m |= (x2.y > 0) ? 512u : 0u;
        m |= (x2.z > 0) ? 1024u : 0u;     m |= (x2.w > 0) ? 2048u : 0u;
        m |= (x3.x > 0) ? 4096u : 0u;     m |= (x3.y > 0) ? 8192u : 0u;
        m |= (x3.z > 0) ? 16384u : 0u;    m |= (x3.w > 0) ? 32768u : 0u;
        bits16[g] = (unsigned short)m;
    }
}

// ---------------------------------------------------------------------------
// Kernel 2: masked softmax + attention@V + ELU.
// o-split 64, k-split 4, grid 1024, dense fragment-major V loads (r8).
// P pack via cvt_pk intrinsics. launch_bounds(256,3), 12 waves/CU.
// Fixed subtractor m_i = lrelu(s1_i + max_k s2_k) -> single pass, no rescale.
// ---------------------------------------------------------------------------
#define IBLK 32

__global__ __launch_bounds__(256, 3) void k_attn(
    const unsigned char* __restrict__ bits, const unsigned short* __restrict__ Vf,
    const float* __restrict__ s1g, const float* __restrict__ s2g,
    float* __restrict__ out)
{
    __shared__ __align__(16) char smem[33792];   // union: [s2 8192 | bits 8320] -> comb
    __shared__ float rs_lds[4][IBLK];
    __shared__ float wmaxs[4];
    __shared__ __align__(16) float lut[16][4];

    float* s2_lds = (float*)smem;
    unsigned int* bitw = (unsigned int*)(smem + 8192);   // [32][65] words, padded
    float* comb = (float*)smem;                           // [4][64][33] floats

    const int t = threadIdx.x, lane = t & 63, w = t >> 6;
    // XCD swizzle: batch = XCD. grid 1024 = 8 batches x (64 row-tiles x 2 o-halves)
    const int orig = blockIdx.x;
    const int b = orig & 7;
    const int r = orig >> 3;
    const int oh = r >> 6;              // o-half: cols oh*64 .. +63
    const int i0 = (r & 63) * IBLK;

    // mask LUT: nibble -> 4 floats
    if (t < 16) {
        lut[t][0] = (float)(t & 1);
        lut[t][1] = (float)((t >> 1) & 1);
        lut[t][2] = (float)((t >> 2) & 1);
        lut[t][3] = (float)((t >> 3) & 1);
    }

    // ---- stage bits: 32 rows x 64 words -> padded stride 65 (bank-clean) ----
    {
        const unsigned int* bg = (const unsigned int*)(bits + ((size_t)b * NN + i0) * 256);
#pragma unroll
        for (int q = 0; q < 8; ++q) {
            const int idx = q * 256 + t;   // 0..2047
            bitw[(idx >> 6) * 65 + (idx & 63)] = bg[idx];
        }
    }

    // ---- stage s2 (full row) + global max ----
    const float4* s2v = (const float4*)(s2g + b * NN);
    float lmax = -1e30f;
#pragma unroll
    for (int q = 0; q < 2; ++q) {
        const int idx = q * 256 + t;
        const float4 v = s2v[idx];
        ((float4*)s2_lds)[idx] = v;
        lmax = fmaxf(fmaxf(lmax, fmaxf(v.x, v.y)), fmaxf(v.z, v.w));
    }
#pragma unroll
    for (int off = 32; off; off >>= 1) lmax = fmaxf(lmax, __shfl_xor(lmax, off));
    if (lane == 0) wmaxs[w] = lmax;

    const int irow = lane & 15;     // subtile-local row
    const int kcb = lane >> 4;      // k-strip 0..3 within a 32-k step
    const int kw = w * 512;         // this wave's k-range

    const float s1r0 = s1g[b * NN + i0 + irow];
    const float s1r1 = s1g[b * NN + i0 + 16 + irow];
    __syncthreads();
    const float s2max = fmaxf(fmaxf(wmaxs[0], wmaxs[1]), fmaxf(wmaxs[2], wmaxs[3]));
    const float mx0 = s1r0 + s2max, mx1 = s1r1 + s2max;
    const float mA0 = fmaxf(mx0, ALPHA * mx0);
    const float mA1 = fmaxf(mx1, ALPHA * mx1);

    const float* s2p = s2_lds + kw + kcb * 8;
    const char* vfb = (const char*)Vf + (size_t)b * 524288 + (size_t)(w * 16) * 8192
                    + (size_t)(oh * 64 + irow) * 64 + (size_t)kcb * 16;
    const unsigned int* bw0p = bitw + irow * 65 + w * 16;
    const unsigned int* bw1p = bitw + (16 + irow) * 65 + w * 16;

    short8v vone;
#pragma unroll
    for (int q = 0; q < 8; ++q) vone[q] = (short)0x3F80;  // bf16 1.0

    f32x4 acc0[4], acc1[4];
    f32x4 acc_ps0 = {0.f, 0.f, 0.f, 0.f}, acc_ps1 = {0.f, 0.f, 0.f, 0.f};
#pragma unroll
    for (int og = 0; og < 4; ++og) {
        acc0[og] = (f32x4){0.f, 0.f, 0.f, 0.f};
        acc1[og] = (f32x4){0.f, 0.f, 0.f, 0.f};
    }

#pragma unroll
    for (int ks = 0; ks < 16; ++ks) {
        // V fragments: dense 1 KB loads (loads first: P-compute covers latency)
        const char* vk = vfb + (size_t)ks * 8192;
        const short8v vf0 = *(const short8v*)(vk);
        const short8v vf1 = *(const short8v*)(vk + 1024);
        const short8v vf2 = *(const short8v*)(vk + 2048);
        const short8v vf3 = *(const short8v*)(vk + 3072);

        const unsigned int bb0 = (bw0p[ks] >> (kcb * 8)) & 0xffu;
        const unsigned int bb1 = (bw1p[ks] >> (kcb * 8)) & 0xffu;
        const float4 m00 = ((const float4*)lut)[bb0 & 15], m01 = ((const float4*)lut)[bb0 >> 4];
        const float4 m10 = ((const float4*)lut)[bb1 & 15], m11 = ((const float4*)lut)[bb1 >> 4];

        const float4 sa = *(const float4*)(s2p + ks * 32);
        const float4 sb = *(const float4*)(s2p + ks * 32 + 4);
        const float s2r[8] = {sa.x, sa.y, sa.z, sa.w, sb.x, sb.y, sb.z, sb.w};
        const float mk0[8] = {m00.x, m00.y, m00.z, m00.w, m01.x, m01.y, m01.z, m01.w};
        const float mk1[8] = {m10.x, m10.y, m10.z, m10.w, m11.x, m11.y, m11.z, m11.w};

        float p0[8], p1[8];
#pragma unroll
        for (int e = 0; e < 8; ++e) {
            float x0 = s1r0 + s2r[e];
            x0 = fmaxf(x0, ALPHA * x0);
            p0[e] = __expf(x0 - mA0) * mk0[e];
            float x1 = s1r1 + s2r[e];
            x1 = fmaxf(x1, ALPHA * x1);
            p1[e] = __expf(x1 - mA1) * mk1[e];
        }
        union { short8v v; __hip_bfloat162 h2[4]; } pb0, pb1;
#pragma unroll
        for (int q = 0; q < 4; ++q) {
            pb0.h2[q] = __float22bfloat162_rn(make_float2(p0[2 * q], p0[2 * q + 1]));
            pb1.h2[q] = __float22bfloat162_rn(make_float2(p1[2 * q], p1[2 * q + 1]));
        }

        // psum via ones-row MFMA (sums all 32 k of the step in f32)
        acc_ps0 = __builtin_amdgcn_mfma_f32_16x16x32_bf16(vone, pb0.v, acc_ps0, 0, 0, 0);
        acc_ps1 = __builtin_amdgcn_mfma_f32_16x16x32_bf16(vone, pb1.v, acc_ps1, 0, 0, 0);
        acc0[0] = __builtin_amdgcn_mfma_f32_16x16x32_bf16(vf0, pb0.v, acc0[0], 0, 0, 0);
        acc1[0] = __builtin_amdgcn_mfma_f32_16x16x32_bf16(vf0, pb1.v, acc1[0], 0, 0, 0);
        acc0[1] = __builtin_amdgcn_mfma_f32_16x16x32_bf16(vf1, pb0.v, acc0[1], 0, 0, 0);
        acc1[1] = __builtin_amdgcn_mfma_f32_16x16x32_bf16(vf1, pb1.v, acc1[1], 0, 0, 0);
        acc0[2] = __builtin_amdgcn_mfma_f32_16x16x32_bf16(vf2, pb0.v, acc0[2], 0, 0, 0);
        acc1[2] = __builtin_amdgcn_mfma_f32_16x16x32_bf16(vf2, pb1.v, acc1[2], 0, 0, 0);
        acc0[3] = __builtin_amdgcn_mfma_f32_16x16x32_bf16(vf3, pb0.v, acc0[3], 0, 0, 0);
        acc1[3] = __builtin_amdgcn_mfma_f32_16x16x32_bf16(vf3, pb1.v, acc1[3], 0, 0, 0);
    }

    // ---- wave-partial row sums: every lane already holds its row's total ----
    if (lane < 16) {
        rs_lds[w][lane] = acc_ps0[0];
        rs_lds[w][16 + lane] = acc_ps1[0];
    }

    __syncthreads();  // s2/bits dead; smem becomes comb
#pragma unroll
    for (int og = 0; og < 4; ++og) {
#pragma unroll
        for (int rr = 0; rr < 4; ++rr) {
            const int ol = og * 16 + kcb * 4 + rr;
            comb[(w * 64 + ol) * 33 + irow] = acc0[og][rr];
            comb[(w * 64 + ol) * 33 + 16 + irow] = acc1[og][rr];
        }
    }
    __syncthreads();

    // ---- combine 4 wave-partials, normalize, ELU, coalesced f32 store ----
    const int i = t >> 3, oc = t & 7;
    const float tot = rs_lds[0][i] + rs_lds[1][i] + rs_lds[2][i] + rs_lds[3][i];
    const float inv = 1.0f / tot;
    float res[8];
#pragma unroll
    for (int u = 0; u < 8; ++u) {
        const int ol = oc * 8 + u;
        float v = comb[ol * 33 + i] + comb[(64 + ol) * 33 + i]
                + comb[(128 + ol) * 33 + i] + comb[(192 + ol) * 33 + i];
        v *= inv;
        res[u] = (v > 0.f) ? v : expm1f(v);
    }
    float4* ob = (float4*)(out + ((size_t)b * NN + i0 + i) * OUT_F + oh * 64 + oc * 8);
    ob[0] = make_float4(res[0], res[1], res[2], res[3]);
    ob[1] = make_float4(res[4], res[5], res[6], res[7]);
}

// ---------------------------------------------------------------------------
extern "C" void kernel_launch(void* const* d_in, const int* in_sizes, int n_in,
                              void* d_out, int out_size, void* d_ws, size_t ws_size,
                              hipStream_t stream) {
    const float* h  = (const float*)d_in[0];
    const float* j  = (const float*)d_in[1];
    const int* adj  = (const int*)d_in[2];
    const float* W1 = (const float*)d_in[3];
    const float* W2 = (const float*)d_in[4];
    const float* a  = (const float*)d_in[5];
    float* out = (float*)d_out;

    char* ws = (char*)d_ws;
    unsigned short* Vf = (unsigned short*)ws;               // 4 MB fragment-major
    ws += (size_t)BATCH * OUT_F * NN * 2;
    float* s1 = (float*)ws; ws += (size_t)BATCH * NN * 4;   // 64 KB
    float* s2 = (float*)ws; ws += (size_t)BATCH * NN * 4;   // 64 KB
    unsigned short* Wt = (unsigned short*)ws; ws += 128 * 512 * 2;  // 128 KB
    float* w1a1 = (float*)ws; ws += 512 * 4;
    float* w1a2 = (float*)ws; ws += 512 * 4;
    unsigned char* bits = (unsigned char*)ws;               // B*N*N/8 = 4 MB

    k_prew<<<64, 256, 0, stream>>>(W1, W2, a, Wt, w1a1, w1a2);
    k_proj<<<(BATCH * NN) / BM, 256, 0, stream>>>(h, j, Wt, w1a1, w1a2, adj,
                                                  Vf, s1, s2, (unsigned short*)bits);
    k_attn<<<(BATCH * NN) / IBLK * 2, 256, 0, stream>>>(bits, Vf, s1, s2, out);
}